// Round 8
// baseline (153.497 us; speedup 1.0000x reference)
//
#include <hip/hip_runtime.h>
#include <math.h>

#define WID 512
#define HEI 512
#define NB  16
#define HW  ((size_t)HEI * WID)
#define NEG_INF (-INFINITY)

typedef float f4 __attribute__((ext_vector_type(4)));

__device__ __forceinline__ float qmax4(f4 v) {
    return fmaxf(fmaxf(v.x, v.y), fmaxf(v.z, v.w));
}

// Horizontal 35-max: output cols 4*c4+d (d=0..3) from one sm row; reads f4
// [c4, c4+10] (sm float x = image col x-20; halo = -inf). HW-verified
// (R5/R7, absmax=0.0).
__device__ __forceinline__ f4 hwin35(const f4* __restrict__ rp, int c4) {
    f4 vv[11];
    #pragma unroll
    for (int i = 0; i < 11; ++i) vv[i] = rp[c4 + i];
    float q[10];
    #pragma unroll
    for (int i = 1; i <= 9; ++i) q[i] = qmax4(vv[i]);
    float Q28 = fmaxf(fmaxf(fmaxf(q[2], q[3]), fmaxf(q[4], q[5])),
                      fmaxf(fmaxf(q[6], q[7]), q[8]));
    float Q18 = fmaxf(Q28, q[1]);
    float Q29 = fmaxf(Q28, q[9]);
    float s01 = fmaxf(vv[9].x, vv[9].y);
    float s23 = fmaxf(vv[1].z, vv[1].w);
    f4 o;
    o.x = fmaxf(fmaxf(Q18, vv[0].w), s01);
    o.y = fmaxf(Q18, fmaxf(s01, vv[9].z));
    o.z = fmaxf(fmaxf(Q29, vv[1].y), s23);
    o.w = fmaxf(Q29, fmaxf(s23, vv[10].x));
    return o;
}

// -------------------------------------------------------------------------
// Kernel A: channel-min + horizontal 35-max. 4 rows/block (one wave/row).
// Lane l handles image f4 l and l+64: all global & LDS accesses are
// consecutive-lane-consecutive-16B (no bank aliasing). Unchanged from R7
// (measured as part of 56 us kernel total). Also zeroes acc (block 0,0).
// -------------------------------------------------------------------------
__global__ __launch_bounds__(256) void hmax_kernel(
    const float* __restrict__ rin, const float* __restrict__ tin,
    float* __restrict__ ws, float* __restrict__ acc)
{
    __shared__ float sm[4][552];     // 20 halo + 512 + 20 halo floats
    const int tid = threadIdx.x;
    const int wv  = tid >> 6;        // wave = row within block
    const int l   = tid & 63;
    const int h   = blockIdx.x * 4 + wv;
    const int z   = blockIdx.y;      // tensor*16 + b
    const int b   = z & 15;
    const float* __restrict__ in = (z < NB) ? rin : tin;
    const float* __restrict__ p  = in + (size_t)b * 3 * HW + (size_t)h * WID;

    // zero [sum, ticket]; visible to vmax at kernel boundary (R3-proven)
    if (blockIdx.x == 0 && blockIdx.y == 0 && tid < 2) acc[tid] = 0.0f;

    if (tid < 160) {                 // -inf halo for the block's 4 rows
        int r = tid / 40, j = tid % 40;
        sm[r][(j < 20) ? j : (j + 512)] = NEG_INF;
    }

    const f4* __restrict__ p0 = (const f4*)p;
    const f4* __restrict__ p1 = (const f4*)(p + HW);
    const f4* __restrict__ p2 = (const f4*)(p + 2 * HW);
    f4 a0 = __builtin_nontemporal_load(p0 + l);
    f4 b0 = __builtin_nontemporal_load(p1 + l);
    f4 c0 = __builtin_nontemporal_load(p2 + l);
    f4 a1 = __builtin_nontemporal_load(p0 + l + 64);
    f4 b1 = __builtin_nontemporal_load(p1 + l + 64);
    f4 c1 = __builtin_nontemporal_load(p2 + l + 64);
    f4 v0, v1;
    v0.x = fminf(fminf(a0.x, b0.x), c0.x);
    v0.y = fminf(fminf(a0.y, b0.y), c0.y);
    v0.z = fminf(fminf(a0.z, b0.z), c0.z);
    v0.w = fminf(fminf(a0.w, b0.w), c0.w);
    v1.x = fminf(fminf(a1.x, b1.x), c1.x);
    v1.y = fminf(fminf(a1.y, b1.y), c1.y);
    v1.z = fminf(fminf(a1.z, b1.z), c1.z);
    v1.w = fminf(fminf(a1.w, b1.w), c1.w);
    *(f4*)&sm[wv][20 + 4 * l]        = v0;
    *(f4*)&sm[wv][20 + 4 * (l + 64)] = v1;
    __syncthreads();

    const f4* __restrict__ smr = (const f4*)sm[wv];
    f4 o0 = hwin35(smr, l);
    f4 o1 = hwin35(smr, l + 64);
    f4* __restrict__ wp = (f4*)(ws + (size_t)z * HW + (size_t)h * WID);
    wp[l]      = o0;
    wp[l + 64] = o1;
}

// -------------------------------------------------------------------------
// Kernel B: vertical 35-max (both tensors) + |r-t| + reduce + ticket
// finalize. 64-tall x 64-wide tiles: LDS 25.1 KB -> 6 blocks/CU =
// 24 waves/CU (2x TLP of the 128-tall variant; halo re-reads are L2/L3
// hits so the 1.53x factor is cheap). grid (8,8,16) = 1024 blocks.
// Quad-max math HW-verified (R3, exact tile shape, absmax=0.0).
// -------------------------------------------------------------------------
__global__ __launch_bounds__(256, 6) void vmax_kernel(
    const float* __restrict__ ws, float* __restrict__ acc,
    float* __restrict__ out)
{
    __shared__ float cm[98][64];     // region rows [h0-17, h0+80]
    __shared__ float red[4];
    const int tid = threadIdx.x;
    const int col = tid & 63;
    const int ty  = tid >> 6;        // wave: output rows ty*16 .. ty*16+15
    const int w0  = blockIdx.x * 64;
    const int h0  = blockIdx.y * 64;
    const int b   = blockIdx.z;

    float rtv[16];
    float tsum = 0.0f;

    #pragma unroll
    for (int tensor = 0; tensor < 2; ++tensor) {
        const float* __restrict__ pb = ws + (size_t)(tensor * NB + b) * HW;

        for (int i = tid; i < 1568; i += 256) {   // 98 rows x 16 f4
            int r = i >> 4, c4 = i & 15;
            int hh = h0 - 17 + r;
            f4 v = {NEG_INF, NEG_INF, NEG_INF, NEG_INF};
            if (hh >= 0 && hh < HEI)
                v = ((const f4*)pb)[hh * 128 + (w0 >> 2) + c4];
            *(f4*)&cm[r][4 * c4] = v;
        }
        __syncthreads();

        float vc[50];
        #pragma unroll
        for (int i = 0; i < 50; ++i) vc[i] = cm[ty * 16 + i][col];
        float q[12];
        #pragma unroll
        for (int i = 0; i < 12; ++i)
            q[i] = fmaxf(fmaxf(vc[4*i], vc[4*i+1]), fmaxf(vc[4*i+2], vc[4*i+3]));
        #pragma unroll
        for (int m = 0; m < 4; ++m) {
            float Qc = fmaxf(fmaxf(fmaxf(q[m+1], q[m+2]), fmaxf(q[m+3], q[m+4])),
                             fmaxf(fmaxf(q[m+5], q[m+6]), q[m+7]));
            float A  = fmaxf(Qc, q[m+8]);
            float o0 = fmaxf(fmaxf(Qc, q[m]),
                             fmaxf(fmaxf(vc[4*m+32], vc[4*m+33]), vc[4*m+34]));
            float o1 = fmaxf(A, fmaxf(fmaxf(vc[4*m+1], vc[4*m+2]), vc[4*m+3]));
            float o2 = fmaxf(A, fmaxf(fmaxf(vc[4*m+2], vc[4*m+3]), vc[4*m+36]));
            float o3 = fmaxf(A, fmaxf(fmaxf(vc[4*m+3], vc[4*m+36]), vc[4*m+37]));
            if (tensor == 0) {
                rtv[4*m] = o0; rtv[4*m+1] = o1; rtv[4*m+2] = o2; rtv[4*m+3] = o3;
            } else {
                tsum += fabsf(rtv[4*m]   - o0) + fabsf(rtv[4*m+1] - o1)
                      + fabsf(rtv[4*m+2] - o2) + fabsf(rtv[4*m+3] - o3);
            }
        }
        __syncthreads();   // protect cm before next tensor staging
    }

    // wave shuffle reduce -> 4 partials -> atomic + ticket finalize
    #pragma unroll
    for (int off = 32; off > 0; off >>= 1)
        tsum += __shfl_down(tsum, off, 64);
    if (col == 0) red[ty] = tsum;
    __syncthreads();
    if (tid == 0) {
        float bs = red[0] + red[1] + red[2] + red[3];
        atomicAdd(acc, bs);
        __threadfence();
        unsigned tk = atomicAdd((unsigned*)(acc + 1), 1u);
        if (tk == 1023u) {                      // last of 1024 blocks
            float s = atomicAdd(acc, 0.0f);     // coherent final sum
            out[0] = 1.0f / (1.0f + expf(-s / 4194304.0f));
        }
    }
}

// -------------------------------------------------------------------------
extern "C" void kernel_launch(void* const* d_in, const int* in_sizes, int n_in,
                              void* d_out, int out_size, void* d_ws, size_t ws_size,
                              hipStream_t stream) {
    const float* rin = (const float*)d_in[0];   // restored [16,3,512,512]
    const float* tin = (const float*)d_in[1];   // target   [16,3,512,512]
    float* out = (float*)d_out;

    float* wsf = (float*)d_ws;                  // [2][16][512][512] + acc
    float* acc = wsf + (size_t)2 * NB * HW;     // [sum, ticket]

    dim3 gA(HEI / 4, 2 * NB);
    hipLaunchKernelGGL(hmax_kernel, gA, dim3(256), 0, stream, rin, tin, wsf, acc);

    dim3 gB(WID / 64, HEI / 64, NB);
    hipLaunchKernelGGL(vmax_kernel, gB, dim3(256), 0, stream, wsf, acc, out);
}